// Round 12
// baseline (675.261 us; speedup 1.0000x reference)
//
#include <hip/hip_runtime.h>

// Problem constants (fixed by the reference setup_inputs)
#define V_N   50000
#define B_N   4
#define C_IN  128
#define C_OUT 128
#define E_N   800000
#define F_N   512                 // B_N * C_IN features per vertex
#define M_TOT 200000              // V_N * B_N rows of the (v,b) GEMM view

#define SCAN_BLK  1024                        // elements per scan block (256 thr x 4)
#define SCAN_NB   ((V_N + SCAN_BLK - 1) / SCAN_BLK)   // 49

// fused prep-kernel block ranges
#define NTB_V   ((V_N + 127) / 128)           // 391 transpose v-blocks
#define NTB     (NTB_V * 16)                  // 6256 transpose blocks
#define NHB     ((E_N + 255) / 256)           // 3125 hist blocks
#define NWB     64                            // wprep blocks
#define NPREP   (NTB + NHB + NWB)             // 9445

typedef unsigned short ushort_t;
typedef __attribute__((ext_vector_type(8))) short short8;   // 8 bf16 (4 VGPRs)
typedef __attribute__((ext_vector_type(4))) float f32x4;

#define AS1 __attribute__((address_space(1)))
#define AS3 __attribute__((address_space(3)))
// async global->LDS DMA, 16 B per lane. LDS dest: wave-uniform base + lane*16.
__device__ __forceinline__ void gl_lds16(const void* gp, void* lp) {
    __builtin_amdgcn_global_load_lds((const AS1 unsigned int*)gp,
                                     (AS3 unsigned int*)lp, 16, 0, 0);
}

__device__ __forceinline__ float bf_lo(unsigned u) { return __uint_as_float(u << 16); }
__device__ __forceinline__ float bf_hi(unsigned u) { return __uint_as_float(u & 0xFFFF0000u); }
__device__ __forceinline__ ushort_t f2bf(float f) {      // RNE
    unsigned u = __float_as_uint(f);
    u += 0x7FFFu + ((u >> 16) & 1u);
    return (ushort_t)(u >> 16);
}

// ---------------------------------------------------------------------------
// 1) Fused prep: three independent jobs routed by block range.
//    [0, NTB)          transpose x (B,Cin,V) fp32 -> x0 (V,F) bf16
//    [NTB, NTB+NHB)    histogram of edge_row into counts
//    [NTB+NHB, NPREP)  Chebyshev-folded weight prep -> Wt (k,o,c) bf16
// ---------------------------------------------------------------------------
__global__ __launch_bounds__(256) void k_prep(const float* __restrict__ x,
                                              ushort_t* __restrict__ x0,
                                              const int* __restrict__ edge_row,
                                              int* __restrict__ counts,
                                              const float* __restrict__ W,
                                              ushort_t* __restrict__ Wt) {
    __shared__ float tile[32][133];   // [f][v] (transpose branch only)
    int b = blockIdx.x;
    int tid = threadIdx.x;

    if (b < NTB) {
        // ---- transpose: float4 reads, LDS tile, uint2 bf16 writes ----
        int vb = (b % NTB_V) * 128;
        int fb = (b / NTB_V) * 32;
        int fo = tid >> 5;               // 0..7
        int vo = (tid & 31) * 4;         // 0..124
#pragma unroll
        for (int p = 0; p < 4; p++) {
            int f = fb + fo + p * 8;
            int v = vb + vo;
            float4 val = make_float4(0.f, 0.f, 0.f, 0.f);
            const float* xp = &x[(size_t)f * V_N + v];
            if (v + 3 < V_N) {
                val = *(const float4*)xp;
            } else {
                if (v     < V_N) val.x = xp[0];
                if (v + 1 < V_N) val.y = xp[1];
                if (v + 2 < V_N) val.z = xp[2];
                if (v + 3 < V_N) val.w = xp[3];
            }
            tile[fo + p * 8][vo + 0] = val.x;
            tile[fo + p * 8][vo + 1] = val.y;
            tile[fo + p * 8][vo + 2] = val.z;
            tile[fo + p * 8][vo + 3] = val.w;
        }
        __syncthreads();
        int fl = (tid & 7) * 4;          // 0,4,..,28
        int vbase = tid >> 3;            // 0..31
#pragma unroll
        for (int i = 0; i < 4; i++) {
            int vloc = vbase + i * 32;
            int v = vb + vloc;
            if (v < V_N) {
                ushort_t r[4] = { f2bf(tile[fl + 0][vloc]), f2bf(tile[fl + 1][vloc]),
                                  f2bf(tile[fl + 2][vloc]), f2bf(tile[fl + 3][vloc]) };
                *(uint2*)&x0[(size_t)v * F_N + fb + fl] = *(const uint2*)r;
            }
        }
    } else if (b < NTB + NHB) {
        // ---- histogram ----
        int e = (b - NTB) * 256 + tid;
        if (e < E_N) atomicAdd(&counts[edge_row[e]], 1);
    } else {
        // ---- weight prep, Chebyshev folding:
        //      z0(W0-W2) + z1(W1-3W3) + z2(2W2) + z3(4W3) ----
        int i = (b - NTB - NHB) * 256 + tid;      // 16384 total: (c,o)
        int c = i >> 7, o = i & 127;
        float w0 = W[0 * 16384 + c * 128 + o];
        float w1 = W[1 * 16384 + c * 128 + o];
        float w2 = W[2 * 16384 + c * 128 + o];
        float w3 = W[3 * 16384 + c * 128 + o];
        Wt[((size_t)0 * 128 + o) * 128 + c] = f2bf(w0 - w2);
        Wt[((size_t)1 * 128 + o) * 128 + c] = f2bf(w1 - 3.f * w3);
        Wt[((size_t)2 * 128 + o) * 128 + c] = f2bf(2.f * w2);
        Wt[((size_t)3 * 128 + o) * 128 + c] = f2bf(4.f * w3);
    }
}

// ---------------------------------------------------------------------------
// 2) CSR build: scan stage 1 -> fused offset+add stage -> scatter
// ---------------------------------------------------------------------------
__global__ __launch_bounds__(256) void k_scan_blk(const int* __restrict__ counts,
                                                  int* __restrict__ row_ptr,
                                                  int* __restrict__ blk_sums) {
    __shared__ int s[256];
    int t = threadIdx.x;
    int base = blockIdx.x * SCAN_BLK + t * 4;
    int c0 = (base + 0 < V_N) ? counts[base + 0] : 0;
    int c1 = (base + 1 < V_N) ? counts[base + 1] : 0;
    int c2 = (base + 2 < V_N) ? counts[base + 2] : 0;
    int c3 = (base + 3 < V_N) ? counts[base + 3] : 0;
    int p1 = c0, p2 = c0 + c1, p3 = c0 + c1 + c2, tot = p3 + c3;
    s[t] = tot;
    __syncthreads();
#pragma unroll
    for (int off = 1; off < 256; off <<= 1) {
        int v = (t >= off) ? s[t - off] : 0;
        __syncthreads();
        s[t] += v;
        __syncthreads();
    }
    int excl = (t == 0) ? 0 : s[t - 1];
    if (base + 0 < V_N) row_ptr[base + 0] = excl;
    if (base + 1 < V_N) row_ptr[base + 1] = excl + p1;
    if (base + 2 < V_N) row_ptr[base + 2] = excl + p2;
    if (base + 3 < V_N) row_ptr[base + 3] = excl + p3;
    if (t == 255) blk_sums[blockIdx.x] = s[255];
}

// Stage 2+3 fused: each block re-derives its global offset from blk_sums.
__global__ __launch_bounds__(256) void k_scan_add(const int* __restrict__ blk_sums,
                                                  int* __restrict__ row_ptr,
                                                  int* __restrict__ next) {
    __shared__ int off_s, tot_s;
    int b = blockIdx.x, t = threadIdx.x;
    if (t < 64) {
        int v  = (t < SCAN_NB) ? blk_sums[t] : 0;
        int pv = (t < b) ? v : 0;
#pragma unroll
        for (int o = 32; o; o >>= 1) {
            pv += __shfl_down(pv, o);
            v  += __shfl_down(v, o);
        }
        if (t == 0) { off_s = pv; tot_s = v; }
    }
    __syncthreads();
    int off = off_s;
    int base = b * SCAN_BLK + t * 4;
#pragma unroll
    for (int i = 0; i < 4; i++) {
        int idx = base + i;
        if (idx < V_N) {
            int rv = row_ptr[idx] + off;
            row_ptr[idx] = rv;
            next[idx]    = rv;
        }
    }
    if (b == 0 && t == 0) row_ptr[V_N] = tot_s;
}

__global__ __launch_bounds__(256) void k_scatter(const int* __restrict__ row,
                                                 const int* __restrict__ col,
                                                 const float* __restrict__ vals,
                                                 int* __restrict__ next,
                                                 int2* __restrict__ edges) {
    int e = blockIdx.x * blockDim.x + threadIdx.x;
    if (e < E_N) {
        int r = row[e];
        int pos = atomicAdd(&next[r], 1);
        edges[pos] = make_int2(col[e], __float_as_int(vals[e]));
    }
}

// ---------------------------------------------------------------------------
// 4) Pure-power SpMM (bf16, fp32 accumulate): dst = A * src.
//    r8 wave decomposition + memory pattern (empirical floor across 5
//    pattern variants). NEW: explicit 2-deep software pipeline — iteration
//    i+1's edge loads and gathers are issued BEFORE iteration i's FMAs, so
//    each wave always has >=4 gathers in flight instead of exposing a full
//    gather latency per 4 edges (VGPR 20 showed the compiler serialized).
//    Identical traffic; only scheduling depth changes.
// ---------------------------------------------------------------------------
__global__ __launch_bounds__(256) void k_spmm_bf16(const int* __restrict__ row_ptr,
                                                   const int2* __restrict__ edges,
                                                   const ushort_t* __restrict__ src,
                                                   ushort_t* __restrict__ dst) {
    int lane = threadIdx.x & 63;
    int g = blockIdx.x * 4 + (threadIdx.x >> 6);   // global wave id
    int r = g >> 1;
    int h = g & 1;                                  // feature half
    int e0 = row_ptr[r], e1 = row_ptr[r + 1];
    float a0 = 0.f, a1 = 0.f, a2 = 0.f, a3 = 0.f;
    const ushort_t* sp = src + h * 256 + lane * 4;

#define GATHER(E_) (*(const uint2*)(sp + (size_t)(E_).x * F_N))
#define ACC4(E_, G_)                                                     \
    {                                                                    \
        float w_ = __int_as_float((E_).y);                               \
        a0 += w_ * bf_lo((G_).x); a1 += w_ * bf_hi((G_).x);              \
        a2 += w_ * bf_lo((G_).y); a3 += w_ * bf_hi((G_).y);              \
    }

    int e = e0;
    int nfull = (e1 - e0) >> 2;         // full 4-edge groups
    if (nfull > 0) {
        // prologue: issue group 0
        int2 E0 = edges[e], E1 = edges[e + 1], E2 = edges[e + 2], E3 = edges[e + 3];
        uint2 g0 = GATHER(E0), g1 = GATHER(E1), g2 = GATHER(E2), g3 = GATHER(E3);
        for (int it = 1; it < nfull; it++) {
            e += 4;
            // issue group it (edges + gathers) before consuming group it-1
            int2 F0 = edges[e], F1 = edges[e + 1], F2 = edges[e + 2], F3 = edges[e + 3];
            uint2 n0 = GATHER(F0), n1 = GATHER(F1), n2 = GATHER(F2), n3 = GATHER(F3);
            // consume group it-1
            ACC4(E0, g0); ACC4(E1, g1); ACC4(E2, g2); ACC4(E3, g3);
            // rotate
            E0 = F0; E1 = F1; E2 = F2; E3 = F3;
            g0 = n0; g1 = n1; g2 = n2; g3 = n3;
        }
        // epilogue: consume last group
        ACC4(E0, g0); ACC4(E1, g1); ACC4(E2, g2); ACC4(E3, g3);
        e += 4;
    }
    for (; e < e1; e++) {
        int2 E = edges[e];
        uint2 gv = GATHER(E);
        ACC4(E, gv);
    }
#undef GATHER
#undef ACC4

    size_t off = (size_t)r * F_N + h * 256 + lane * 4;
    ushort_t res[4] = {f2bf(a0), f2bf(a1), f2bf(a2), f2bf(a3)};
    *(uint2*)(dst + off) = *(const uint2*)res;
}

// ---------------------------------------------------------------------------
// 5) MFMA GEMM, 2-phase pipelined (r11; == r7 within noise — kept).
//    Double-buffered LDS, STAGE one step ahead, one barrier per step.
//    Epilogue Cs aliases the dead pipeline buffers (64 KB, 2 blocks/CU).
// ---------------------------------------------------------------------------
__global__ __launch_bounds__(256, 2) void k_gemm_mfma(
        const ushort_t* __restrict__ X0, const ushort_t* __restrict__ X1,
        const ushort_t* __restrict__ X2, const ushort_t* __restrict__ X3,
        const ushort_t* __restrict__ Wt, const float* __restrict__ bias,
        float* __restrict__ out) {
    // [buf][A=0/B=1][row][col] : 2*2*128*64*2B = 64 KB
    __shared__ __align__(16) ushort_t smem[2][2][128][64];

    int tid  = threadIdx.x;
    int lane = tid & 63;
    int wv   = tid >> 6;
    int wm = wv >> 1, wn = wv & 1;
    int quad = lane >> 4, l15 = lane & 15;
    int m_blk = blockIdx.x * 128;

    f32x4 acc[4][4];
#pragma unroll
    for (int fi = 0; fi < 4; fi++)
#pragma unroll
        for (int fj = 0; fj < 4; fj++) {
            acc[fi][fj][0] = 0.f; acc[fi][fj][1] = 0.f;
            acc[fi][fj][2] = 0.f; acc[fi][fj][3] = 0.f;
        }

    const ushort_t* Xb[4] = {X0, X1, X2, X3};

    // staging geometry: one DMA inst = 64 lanes x 16 B = 1 KB = 8 rows of 128 B.
    int rr_s = lane >> 3;              // row within 8-row group
    int pl   = lane & 7;               // 16B chunk slot within row (LDS side)

#define STAGE_STEP(s, bf)                                                     \
    {                                                                         \
        const ushort_t* A_ = Xb[(s) >> 1];                                    \
        const ushort_t* W_ = Wt + (size_t)((s) >> 1) * (128 * 128);           \
        int kk_ = ((s) & 1) * 64;                                             \
        _Pragma("unroll")                                                     \
        for (int i = 0; i < 4; i++) {                                         \
            int r0 = (wv * 4 + i) * 8;                                        \
            int rr = r0 + rr_s;                                               \
            int pg = pl ^ (rr & 7);                                           \
            int gm = m_blk + rr; if (gm >= M_TOT) gm = M_TOT - 1;             \
            gl_lds16(&A_[(size_t)gm * 128 + kk_ + pg * 8], &smem[bf][0][r0][0]); \
            gl_lds16(&W_[(size_t)rr * 128 + kk_ + pg * 8], &smem[bf][1][r0][0]); \
        }                                                                     \
    }

    STAGE_STEP(0, 0);
    __syncthreads();                   // buf0 ready (implicit vmcnt drain)

    for (int s = 0; s < 8; s++) {
        int bf = s & 1;
        if (s < 7) STAGE_STEP(s + 1, bf ^ 1);   // prefetch next step

        short8 a[2][4], b[2][4];
#pragma unroll
        for (int h = 0; h < 2; h++)
#pragma unroll
            for (int f = 0; f < 4; f++) {
                int ra = wm * 64 + f * 16 + l15;
                int ca = (h * 4 + quad) ^ (ra & 7);
                a[h][f] = *(const short8*)&smem[bf][0][ra][ca * 8];
                int rb = wn * 64 + f * 16 + l15;
                int cb = (h * 4 + quad) ^ (rb & 7);
                b[h][f] = *(const short8*)&smem[bf][1][rb][cb * 8];
            }
#pragma unroll
        for (int h = 0; h < 2; h++)
#pragma unroll
            for (int fi = 0; fi < 4; fi++)
#pragma unroll
                for (int fj = 0; fj < 4; fj++)
                    acc[fi][fj] = __builtin_amdgcn_mfma_f32_16x16x32_bf16(
                        a[h][fi], b[h][fj], acc[fi][fj], 0, 0, 0);

        __syncthreads();   // drains next-step DMA + all waves' reads of buf
    }
#undef STAGE_STEP

    // epilogue: Cs aliases the (dead) pipeline buffers. 64x133 f32 = 34 KB.
    float* Cs = (float*)&smem[0][0][0][0];
#define CS(r_, n_) Cs[(r_) * 133 + (n_)]
    int v_blk = m_blk >> 2;
    for (int h = 0; h < 2; h++) {
        __syncthreads();
        if (wm == h) {
#pragma unroll
            for (int fi = 0; fi < 4; fi++)
#pragma unroll
                for (int fj = 0; fj < 4; fj++) {
                    int ml = fi * 16 + quad * 4;
                    int n  = wn * 64 + fj * 16 + l15;
#pragma unroll
                    for (int reg = 0; reg < 4; reg++)
                        CS(ml + reg, n) = acc[fi][fj][reg];
                }
        }
        __syncthreads();
#pragma unroll
        for (int i = 0; i < 8; i++) {
            int idx = tid + i * 256;          // 0..2047
            int v4  = idx & 3;                // float4-chunk of v
            int o   = (idx >> 2) & 127;
            int b   = idx >> 9;               // 0..3
            int vl  = v4 * 4;
            float bv = bias[o];
            float r0 = CS((vl + 0) * 4 + b, o) + bv;
            float r1 = CS((vl + 1) * 4 + b, o) + bv;
            float r2 = CS((vl + 2) * 4 + b, o) + bv;
            float r3 = CS((vl + 3) * 4 + b, o) + bv;
            int v0 = v_blk + h * 16 + vl;
            float* op = out + ((size_t)b * C_OUT + o) * V_N + v0;
            if (v0 + 3 < V_N) {
                *(float4*)op = make_float4(r0, r1, r2, r3);
            } else {
                if (v0     < V_N) op[0] = r0;
                if (v0 + 1 < V_N) op[1] = r1;
                if (v0 + 2 < V_N) op[2] = r2;
                if (v0 + 3 < V_N) op[3] = r3;
            }
        }
    }
#undef CS
}

// ---------------------------------------------------------------------------
extern "C" void kernel_launch(void* const* d_in, const int* in_sizes, int n_in,
                              void* d_out, int out_size, void* d_ws, size_t ws_size,
                              hipStream_t stream) {
    const float* x        = (const float*)d_in[0];
    const int*   edge_row = (const int*)  d_in[1];
    const int*   edge_col = (const int*)  d_in[2];
    const float* edge_val = (const float*)d_in[3];
    const float* weights  = (const float*)d_in[4];
    const float* biases   = (const float*)d_in[5];
    float* out = (float*)d_out;

    // workspace layout: x0..x3 (bf16, V*F each) | Wt (bf16) | int arrays | edges
    const size_t XSZ = (size_t)V_N * F_N;         // 25.6M elements
    ushort_t* x0 = (ushort_t*)d_ws;
    ushort_t* x1 = x0 + XSZ;
    ushort_t* x2 = x1 + XSZ;
    ushort_t* x3 = x2 + XSZ;
    ushort_t* Wt = x3 + XSZ;                      // 4*128*128
    int* iw      = (int*)(Wt + 4 * 128 * 128);
    int* row_ptr = iw;                            // V+1
    int* counts  = iw + 50016;
    int* nxt     = iw + 100032;
    int* blk_sums= iw + 150048;                   // 49 used (64 reserved)
    int2* edges  = (int2*)(iw + 150176);          // E packed {col, val}
    // total ws ~ 212 MB

    // 1) fused prep: transpose -> x0 | histogram -> counts | weights -> Wt
    hipMemsetAsync(counts, 0, V_N * sizeof(int), stream);
    k_prep<<<NPREP, 256, 0, stream>>>(x, x0, edge_row, counts, weights, Wt);

    // 2) CSR scan + scatter
    k_scan_blk<<<SCAN_NB, 256, 0, stream>>>(counts, row_ptr, blk_sums);
    k_scan_add<<<SCAN_NB, 256, 0, stream>>>(blk_sums, row_ptr, nxt);
    k_scatter<<<(E_N + 255) / 256, 256, 0, stream>>>(edge_row, edge_col, edge_val,
                                                     nxt, edges);

    // 3) Pure power chain z_k = A z_{k-1} (bf16 state, fp32 accumulate)
    k_spmm_bf16<<<V_N * 2 / 4, 256, 0, stream>>>(row_ptr, edges, x0, x1);
    k_spmm_bf16<<<V_N * 2 / 4, 256, 0, stream>>>(row_ptr, edges, x1, x2);
    k_spmm_bf16<<<V_N * 2 / 4, 256, 0, stream>>>(row_ptr, edges, x2, x3);

    // 4) fused MFMA GEMM (folded weights) + bias + transpose to (B,Cout,V)
    k_gemm_mfma<<<(M_TOT + 127) / 128, 256, 0, stream>>>(x0, x1, x2, x3, Wt,
                                                         biases, out);
}